// Round 4
// baseline (31828.918 us; speedup 1.0000x reference)
//
#include <hip/hip_runtime.h>
#include <hip/hip_bf16.h>

// OCRHead: B=4, CIN=720, H=W=128, MID=512, KC=VC=256, NC=19.
// Inputs: float32 (per reference). Outputs: float32.
// d_out = logits[4*19*16384] ++ aux_logits[4*19*16384]
//
// d_ws usage: exactly 64 MiB (X bf16 only). Small f32 scratch lives in the aux
// half of d_out and is overwritten at the very end by the recomputed aux
// logits (race-free: final_fused reads scratch from aux half, writes logits
// half; aux_final runs last and reads only X/aux_w/aux_b).
//
// Exact fusions: q folded into m = q_w^T K (attn logits = scale*m^T x);
// obj never materialized: cls_w@(x+obj) = cls_w@x + attn@g, g = (cls_w@out_w)@v^T.

__device__ __forceinline__ float u_lo(unsigned u) { return __uint_as_float(u << 16); }
__device__ __forceinline__ float u_hi(unsigned u) { return __uint_as_float(u & 0xffff0000u); }
__device__ __forceinline__ float scrub(float v) { return isfinite(v) ? v : 1e4f; }
#define BF2F(h) __bfloat162float(h)

// ---- scratch offsets (bytes) inside the AUX half of d_out (4,980,736 B) ----
#define SO_AUXWT  0ull        // 38,912  f32 [512][19]
#define SO_CLSWT  38912ull    // 38,912  f32 [512][19]
#define SO_SS     77824ull    // 4,096   f32 [512][2]
#define SO_PSUM   81920ull    // 512     (memset 0)
#define SO_CTX    82432ull    // 155,648 (memset 0)
#define SO_KMAT   238080ull   // 77,824
#define SO_VMAT   315904ull   // 77,824
#define SO_FCLS   393728ull   // 19,456
#define SO_MT     413184ull   // 155,648
#define SO_G      568832ull   // 5,776   ; end 574,608 < 4,980,736

// ---- K0: transpose 19x512 weights to [512][19] f32 ----
__global__ __launch_bounds__(256) void prep_kernel(
    const float* __restrict__ aux_w, const float* __restrict__ cls_w,
    float* __restrict__ aux_wt, float* __restrict__ cls_wt) {
  int i = blockIdx.x * 256 + threadIdx.x;
  if (i < 9728) {
    int k = i >> 9, c = i & 511;
    aux_wt[c * 19 + k] = aux_w[i];
    cls_wt[c * 19 + k] = cls_w[i];
  }
}

// ---- K1: conv3x3 (f32 in, bf16 out). 32x32 pixel tile, 16 oc, 2x2 px/thread ----
__global__ __launch_bounds__(256) void conv3x3_kernel(
    const float* __restrict__ feats, const float* __restrict__ w3,
    __hip_bfloat16* __restrict__ X) {
  int b = blockIdx.z;
  int oc0 = blockIdx.y * 16;
  int th = (blockIdx.x >> 2) * 32;
  int tw = (blockIdx.x & 3) * 32;
  int tid = threadIdx.x;
  int ph0 = (tid >> 4) * 2, pw0 = (tid & 15) * 2;

  __shared__ float patch[34 * 34];
  float acc[16][4];
#pragma unroll
  for (int o = 0; o < 16; ++o)
#pragma unroll
    for (int j = 0; j < 4; ++j) acc[o][j] = 0.f;

  const float* fb = feats + (size_t)b * 720 * 16384;
  for (int ci = 0; ci < 720; ++ci) {
    for (int i = tid; i < 1156; i += 256) {
      int r = i / 34, c2 = i - r * 34;
      int gh = th + r - 1, gw = tw + c2 - 1;
      float v = 0.f;
      if ((unsigned)gh < 128u && (unsigned)gw < 128u)
        v = fb[(size_t)ci * 16384 + gh * 128 + gw];
      patch[i] = v;
    }
    __syncthreads();
    float p[4][4];
#pragma unroll
    for (int r = 0; r < 4; ++r)
#pragma unroll
      for (int c = 0; c < 4; ++c)
        p[r][c] = patch[(ph0 + r) * 34 + pw0 + c];
    const float* wrow = w3 + ((size_t)oc0 * 720 + ci) * 9;
#pragma unroll 4
    for (int o = 0; o < 16; ++o) {
      const float* wp = wrow + (size_t)o * 6480;  // uniform -> scalar loads
      float w[9];
#pragma unroll
      for (int k = 0; k < 9; ++k) w[k] = wp[k];
#pragma unroll
      for (int py = 0; py < 2; ++py)
#pragma unroll
        for (int px = 0; px < 2; ++px) {
          float s = acc[o][py * 2 + px];
#pragma unroll
          for (int dh = 0; dh < 3; ++dh)
#pragma unroll
            for (int dw = 0; dw < 3; ++dw)
              s = fmaf(w[dh * 3 + dw], p[py + dh][px + dw], s);
          acc[o][py * 2 + px] = s;
        }
    }
    __syncthreads();
  }
#pragma unroll
  for (int o = 0; o < 16; ++o)
#pragma unroll
    for (int py = 0; py < 2; ++py)
#pragma unroll
      for (int px = 0; px < 2; ++px)
        X[(((size_t)b * 512 + oc0 + o) << 14) + (th + ph0 + py) * 128 + (tw + pw0 + px)] =
            __float2bfloat16(acc[o][py * 2 + px]);
}

// ---- K2: per-channel BN stats -> scale/shift ----
__global__ __launch_bounds__(256) void bn_stats_kernel(
    const __hip_bfloat16* __restrict__ X, const float* __restrict__ gamma,
    const float* __restrict__ beta, float* __restrict__ ss_out) {
  int c = blockIdx.x, tid = threadIdx.x;
  float s = 0.f, ss = 0.f;
  for (int b = 0; b < 4; ++b) {
    const __hip_bfloat16* p = X + (((size_t)b * 512 + c) << 14);
    for (int n = tid * 8; n < 16384; n += 2048) {
      uint4 u = *reinterpret_cast<const uint4*>(p + n);
      unsigned arr[4] = {u.x, u.y, u.z, u.w};
#pragma unroll
      for (int j = 0; j < 4; ++j) {
        float f0 = u_lo(arr[j]), f1 = u_hi(arr[j]);
        s += f0 + f1;
        ss += f0 * f0 + f1 * f1;
      }
    }
  }
#pragma unroll
  for (int off = 32; off > 0; off >>= 1) {
    s += __shfl_down(s, off);
    ss += __shfl_down(ss, off);
  }
  __shared__ float red[8];
  int wid = tid >> 6, lane = tid & 63;
  if (lane == 0) { red[wid] = s; red[4 + wid] = ss; }
  __syncthreads();
  if (tid == 0) {
    s = red[0] + red[1] + red[2] + red[3];
    ss = red[4] + red[5] + red[6] + red[7];
    float mean = s * (1.f / 65536.f);
    float var = ss * (1.f / 65536.f) - mean * mean;
    float gi = gamma[c] * rsqrtf(var + 1e-5f);
    ss_out[c * 2] = gi;
    ss_out[c * 2 + 1] = beta[c] - mean * gi;
  }
}

// ---- K3: x = relu(y*scale+shift) in place (bf16) ----
__global__ __launch_bounds__(256) void bn_apply_kernel(
    __hip_bfloat16* __restrict__ X, const float* __restrict__ ss) {
  size_t idx = ((size_t)blockIdx.x * 256 + threadIdx.x) * 8;
  int c = (int)((idx >> 14) & 511);
  float sc = ss[c * 2], sh = ss[c * 2 + 1];
  uint4 u = *reinterpret_cast<const uint4*>(X + idx);
  unsigned arr[4] = {u.x, u.y, u.z, u.w};
  union { uint4 u; __hip_bfloat16 h[8]; } O;
#pragma unroll
  for (int j = 0; j < 4; ++j) {
    float f0 = fmaxf(fmaf(u_lo(arr[j]), sc, sh), 0.f);
    float f1 = fmaxf(fmaf(u_hi(arr[j]), sc, sh), 0.f);
    O.h[2 * j] = __float2bfloat16(f0);
    O.h[2 * j + 1] = __float2bfloat16(f1);
  }
  *reinterpret_cast<uint4*>(X + idx) = O.u;
}

// ---- K4: aux logits (regs) -> softmax -> ctx/psum accumulation ----
__global__ __launch_bounds__(256) void aux_ctx_kernel(
    const __hip_bfloat16* __restrict__ X, const float* __restrict__ aux_wt,
    const float* __restrict__ aux_b,
    float* __restrict__ ctx, float* __restrict__ psum) {
  int b = blockIdx.y;
  int n0 = blockIdx.x * 512;
  int tid = threadIdx.x;
  __shared__ float pl[19][512];

  const __hip_bfloat16* Xb = X + (((size_t)b * 512) << 14);

  // phase 1: aux logits + softmax for 2 pixels/thread
  int p0 = n0 + tid * 2;
  float a0[19], a1[19];
#pragma unroll
  for (int k = 0; k < 19; ++k) { a0[k] = aux_b[k]; a1[k] = a0[k]; }
  for (int c = 0; c < 512; ++c) {
    unsigned xv = *reinterpret_cast<const unsigned*>(Xb + ((size_t)c << 14) + p0);
    float f0 = u_lo(xv), f1 = u_hi(xv);
    const float* wr = aux_wt + c * 19;  // uniform -> broadcast
#pragma unroll
    for (int k = 0; k < 19; ++k) {
      a0[k] = fmaf(wr[k], f0, a0[k]);
      a1[k] = fmaf(wr[k], f1, a1[k]);
    }
  }
  float mx0 = a0[0], mx1 = a1[0];
#pragma unroll
  for (int k = 1; k < 19; ++k) { mx0 = fmaxf(mx0, a0[k]); mx1 = fmaxf(mx1, a1[k]); }
  float s0 = 0.f, s1 = 0.f;
#pragma unroll
  for (int k = 0; k < 19; ++k) {
    a0[k] = __expf(a0[k] - mx0); s0 += a0[k];
    a1[k] = __expf(a1[k] - mx1); s1 += a1[k];
  }
  float r0 = 1.f / s0, r1 = 1.f / s1;
#pragma unroll
  for (int k = 0; k < 19; ++k) {
    float q0 = a0[k] * r0, q1 = a1[k] * r1;
    pl[k][tid * 2] = q0;
    pl[k][tid * 2 + 1] = q1;
    a0[k] = q0 + q1;  // per-thread psum partial
  }
#pragma unroll
  for (int k = 0; k < 19; ++k) {
    float t = a0[k];
#pragma unroll
    for (int off = 32; off > 0; off >>= 1) t += __shfl_down(t, off);
    if ((tid & 63) == 0) atomicAdd(&psum[b * 19 + k], t);
  }
  __syncthreads();

  // phase 2: ctx accumulation, 2 channels/thread over the 512-pixel chunk
  int c0 = tid * 2;
  const __hip_bfloat16* x0 = Xb + ((size_t)c0 << 14) + n0;
  const __hip_bfloat16* x1 = x0 + 16384;
  float b0[19], b1[19];
#pragma unroll
  for (int k = 0; k < 19; ++k) { b0[k] = 0.f; b1[k] = 0.f; }
  for (int nl = 0; nl < 512; ++nl) {
    float xv0 = BF2F(x0[nl]), xv1 = BF2F(x1[nl]);
#pragma unroll
    for (int kk = 0; kk < 19; ++kk) {
      float p = pl[kk][nl];
      b0[kk] = fmaf(p, xv0, b0[kk]);
      b1[kk] = fmaf(p, xv1, b1[kk]);
    }
  }
#pragma unroll
  for (int kk = 0; kk < 19; ++kk) {
    atomicAdd(&ctx[((b * 19 + kk) << 9) + c0], b0[kk]);
    atomicAdd(&ctx[((b * 19 + kk) << 9) + c0 + 1], b1[kk]);
  }
}

// ---- K5: K = k_w@(ctx/psum)+k_b ; v = v_w@(ctx/psum)+v_b ; fcls = cls_w@out_w ----
__global__ __launch_bounds__(256) void small_a_kernel(
    const float* __restrict__ ctx, const float* __restrict__ psum,
    const float* __restrict__ k_w, const float* __restrict__ k_b,
    const float* __restrict__ v_w, const float* __restrict__ v_b,
    const float* __restrict__ cls_w, const float* __restrict__ out_w,
    float* __restrict__ Kmat, float* __restrict__ vmat, float* __restrict__ fcls) {
  int i = blockIdx.x * 256 + threadIdx.x;
  if (i < 38912) {
    int half = i / 19456;
    int j = i - half * 19456;
    int d = j & 255;
    int t = j >> 8;  // b*19+kk
    const float* w = (half ? v_w : k_w) + d * 512;
    const float* cr = ctx + (t << 9);
    float s = 0.f;
    for (int c = 0; c < 512; ++c) s = fmaf(w[c], cr[c], s);
    float rcp = 1.f / fmaxf(psum[t], 1e-6f);
    float bias = (half ? v_b : k_b)[d];
    (half ? vmat : Kmat)[j] = s * rcp + bias;
  } else if (i < 43776) {
    int j = i - 38912;
    int vv = j & 255, k = j >> 8;
    const float* cw = cls_w + k * 512;
    float s = 0.f;
    for (int c = 0; c < 512; ++c) s = fmaf(cw[c], out_w[c * 256 + vv], s);
    fcls[j] = s;
  }
}

// ---- K6: m[b,c,kk] = sum_d q_w[d,c]*K[b,kk,d] ; g[b,kk,k] = sum_v fcls[k,v]*v[b,kk,v] ----
__global__ __launch_bounds__(256) void small_b_kernel(
    const float* __restrict__ Kmat, const float* __restrict__ vmat,
    const float* __restrict__ fcls, const float* __restrict__ q_w,
    float* __restrict__ m_t, float* __restrict__ g) {
  int i = blockIdx.x * 256 + threadIdx.x;
  if (i < 38912) {
    int kk = i % 19;
    int t = i / 19;  // b*512+c
    int c = t & 511, b = t >> 9;
    const float* kr = Kmat + ((b * 19 + kk) << 8);
    float s = 0.f;
    for (int d = 0; d < 256; ++d) s = fmaf(q_w[d * 512 + c], kr[d], s);
    m_t[i] = s;
  } else if (i < 40356) {
    int j = i - 38912;
    int k = j % 19;
    int t = j / 19;  // b*19+kka
    const float* vr = vmat + (t << 8);
    const float* fr = fcls + (k << 8);
    float s = 0.f;
    for (int v = 0; v < 256; ++v) s = fmaf(fr[v], vr[v], s);
    g[j] = s;
  }
}

// ---- K7: fused attn-softmax + final logits (f32 out, logits half only) ----
__global__ __launch_bounds__(256) void final_fused_kernel(
    const __hip_bfloat16* __restrict__ X, const float* __restrict__ m_t,
    const float* __restrict__ cls_wt, const float* __restrict__ cls_b,
    const float* __restrict__ g, float* __restrict__ out) {
  int b = blockIdx.y;
  int n = blockIdx.x * 256 + threadIdx.x;
  float macc[19], cacc[19];
#pragma unroll
  for (int k = 0; k < 19; ++k) { macc[k] = 0.f; cacc[k] = 0.f; }
  const __hip_bfloat16* xp = X + (((size_t)b * 512) << 14) + n;
  for (int c = 0; c < 512; ++c) {
    float xv = BF2F(xp[(size_t)c << 14]);
    const float* mr = m_t + (b * 512 + c) * 19;   // uniform -> broadcast
    const float* wr = cls_wt + c * 19;            // uniform -> broadcast
#pragma unroll
    for (int k = 0; k < 19; ++k) {
      macc[k] = fmaf(mr[k], xv, macc[k]);
      cacc[k] = fmaf(wr[k], xv, cacc[k]);
    }
  }
  float mx = -1e30f;
#pragma unroll
  for (int k = 0; k < 19; ++k) { macc[k] *= 0.0625f; mx = fmaxf(mx, macc[k]); }
  float sum = 0.f;
#pragma unroll
  for (int k = 0; k < 19; ++k) { macc[k] = __expf(macc[k] - mx); sum += macc[k]; }
  float r = 1.f / sum;
#pragma unroll
  for (int k = 0; k < 19; ++k) cacc[k] += cls_b[k];
#pragma unroll
  for (int kk = 0; kk < 19; ++kk) {
    float av = macc[kk] * r;
    const float* gr = g + (b * 19 + kk) * 19;
#pragma unroll
    for (int k = 0; k < 19; ++k) cacc[k] = fmaf(gr[k], av, cacc[k]);
  }
  size_t ob = ((size_t)b * 19) << 14;
#pragma unroll
  for (int k = 0; k < 19; ++k)
    out[ob + ((size_t)k << 14) + n] = scrub(cacc[k]);
}

// ---- K8 (LAST): recompute aux logits f32, overwriting scratch in aux half ----
__global__ __launch_bounds__(256) void aux_final_kernel(
    const __hip_bfloat16* __restrict__ X, const float* __restrict__ aux_w,
    const float* __restrict__ aux_b, float* __restrict__ aux_out) {
  __shared__ float wt[9728];  // [512][19]
  for (int i = threadIdx.x; i < 9728; i += 256) {
    int k = i >> 9, c = i & 511;
    wt[c * 19 + k] = aux_w[i];
  }
  __syncthreads();
  int b = blockIdx.y;
  int n = blockIdx.x * 256 + threadIdx.x;
  float acc[19];
#pragma unroll
  for (int k = 0; k < 19; ++k) acc[k] = aux_b[k];
  const __hip_bfloat16* xp = X + (((size_t)b * 512) << 14) + n;
  for (int c = 0; c < 512; ++c) {
    float xv = BF2F(xp[(size_t)c << 14]);
    const float* wr = &wt[c * 19];  // uniform -> LDS broadcast
#pragma unroll
    for (int k = 0; k < 19; ++k) acc[k] = fmaf(wr[k], xv, acc[k]);
  }
  size_t ob = ((size_t)b * 19) << 14;
#pragma unroll
  for (int k = 0; k < 19; ++k)
    aux_out[ob + ((size_t)k << 14) + n] = scrub(acc[k]);
}

extern "C" void kernel_launch(void* const* d_in, const int* in_sizes, int n_in,
                              void* d_out, int out_size, void* d_ws, size_t ws_size,
                              hipStream_t stream) {
  const float* feats = (const float*)d_in[0];
  const float* w3    = (const float*)d_in[1];
  const float* gamma = (const float*)d_in[2];
  const float* beta  = (const float*)d_in[3];
  const float* aux_w = (const float*)d_in[4];
  const float* aux_b = (const float*)d_in[5];
  const float* q_w   = (const float*)d_in[6];
  const float* k_w   = (const float*)d_in[7];
  const float* k_b   = (const float*)d_in[8];
  const float* v_w   = (const float*)d_in[9];
  const float* v_b   = (const float*)d_in[10];
  const float* out_w = (const float*)d_in[11];
  const float* cls_w = (const float*)d_in[12];
  const float* cls_b = (const float*)d_in[13];

  float* logits_out = (float*)d_out;
  float* aux_out    = logits_out + 1245184;

  // d_ws: X bf16 only (exactly 64 MiB)
  __hip_bfloat16* X = (__hip_bfloat16*)d_ws;

  // small f32 scratch inside the aux half of d_out (overwritten by aux_final)
  char* sb = (char*)aux_out;
  float* aux_wt = (float*)(sb + SO_AUXWT);
  float* cls_wt = (float*)(sb + SO_CLSWT);
  float* ssbuf  = (float*)(sb + SO_SS);
  float* psum   = (float*)(sb + SO_PSUM);
  float* ctx    = (float*)(sb + SO_CTX);
  float* Kmat   = (float*)(sb + SO_KMAT);
  float* vmat   = (float*)(sb + SO_VMAT);
  float* fcls   = (float*)(sb + SO_FCLS);
  float* m_t    = (float*)(sb + SO_MT);
  float* g      = (float*)(sb + SO_G);

  hipMemsetAsync(sb + SO_PSUM, 0, 512 + 155648, stream);

  prep_kernel<<<38, 256, 0, stream>>>(aux_w, cls_w, aux_wt, cls_wt);
  conv3x3_kernel<<<dim3(16, 32, 4), 256, 0, stream>>>(feats, w3, X);
  bn_stats_kernel<<<512, 256, 0, stream>>>(X, gamma, beta, ssbuf);
  bn_apply_kernel<<<16384, 256, 0, stream>>>(X, ssbuf);
  aux_ctx_kernel<<<dim3(32, 4), 256, 0, stream>>>(X, aux_wt, aux_b, ctx, psum);
  small_a_kernel<<<171, 256, 0, stream>>>(ctx, psum, k_w, k_b, v_w, v_b, cls_w, out_w,
                                          Kmat, vmat, fcls);
  small_b_kernel<<<158, 256, 0, stream>>>(Kmat, vmat, fcls, q_w, m_t, g);
  final_fused_kernel<<<dim3(64, 4), 256, 0, stream>>>(X, m_t, cls_wt, cls_b, g, logits_out);
  aux_final_kernel<<<dim3(64, 4), 256, 0, stream>>>(X, aux_w, aux_b, aux_out);
}

// Round 5
// 1403.818 us; speedup vs baseline: 22.6731x; 22.6731x over previous
//
#include <hip/hip_runtime.h>
#include <hip/hip_bf16.h>

// OCRHead: B=4, CIN=720, H=W=128, MID=512, KC=VC=256, NC=19.
// Inputs/outputs: float32. d_out = logits[1245184] ++ aux_logits[1245184] (f32)
//
// Conv3x3 as MFMA implicit GEMM: out[oc][b,h,w] = sum_{r,dw,ci} W[oc][ci][r][dw]
//   * F[ci][b][h-1+r][w-1+dw]. 9 shift-GEMMs accumulated; K-blocks of 32 ci.
// Weights pre-packed bf16 Apack[9][512][736(pad)]; feats staged per (row,ci-block)
// into LDS [w'=130][r=3][ci pad 40] bf16 (halo cols w'=0,129 zeroed).
//
// d_ws: X bf16 only (64 MiB). Apack + small f32 scratch live inside d_out:
//   Apack at d_out[0..6.78MB)  (consumed by conv; logits half overwritten later)
//   small scratch at tail of aux half (overwritten by aux_final, which runs last)

__device__ __forceinline__ float u_lo(unsigned u) { return __uint_as_float(u << 16); }
__device__ __forceinline__ float u_hi(unsigned u) { return __uint_as_float(u & 0xffff0000u); }
__device__ __forceinline__ float scrub(float v) { return isfinite(v) ? v : 1e4f; }
#define BF2F(h) __bfloat162float(h)

typedef __attribute__((ext_vector_type(8))) short bf16x8;
typedef __attribute__((ext_vector_type(4))) float f32x4;

// ---- d_out scratch offsets (bytes). d_out total = 9,961,472 B ----
#define SO_APACK  0ull            // 9*512*736*2 = 6,782,976
#define TAIL0     9371648ull      // = 9,961,472 - 589,824
#define TA_AUXWT  (TAIL0 + 0ull)       // 38,912
#define TA_CLSWT  (TAIL0 + 38912ull)   // 38,912
#define TA_SS     (TAIL0 + 77824ull)   // 4,096
#define TA_PSUM   (TAIL0 + 81920ull)   // 512    (memset 0)
#define TA_CTX    (TAIL0 + 82432ull)   // 155,648 (memset 0)
#define TA_KMAT   (TAIL0 + 238080ull)  // 77,824
#define TA_VMAT   (TAIL0 + 315904ull)  // 77,824
#define TA_FCLS   (TAIL0 + 393728ull)  // 19,456
#define TA_MT     (TAIL0 + 413184ull)  // 155,648
#define TA_G      (TAIL0 + 568832ull)  // 5,776  ; end 574,608 < 589,824

// LDS B-tile geometry (elements)
#define LDS_CI   40              // padded ci stride (16B-aligned frag reads)
#define LDS_ROW  (3 * LDS_CI)    // 120 per w' column
#define LDS_TOT  (130 * LDS_ROW) // 15,600 elements = 31,200 B

// ---- K0: transpose 19x512 weights to [512][19] f32 ----
__global__ __launch_bounds__(256) void prep_small_kernel(
    const float* __restrict__ aux_w, const float* __restrict__ cls_w,
    float* __restrict__ aux_wt, float* __restrict__ cls_wt) {
  int i = blockIdx.x * 256 + threadIdx.x;
  if (i < 9728) {
    int k = i >> 9, c = i & 511;
    aux_wt[c * 19 + k] = aux_w[i];
    cls_wt[c * 19 + k] = cls_w[i];
  }
}

// ---- K0b: pack conv weights f32 [512][720][3][3] -> bf16 Apack[9][512][736] ----
__global__ __launch_bounds__(256) void prep_apack_kernel(
    const float* __restrict__ w3, __hip_bfloat16* __restrict__ Apack) {
  int idx = blockIdx.x * 256 + threadIdx.x;
  if (idx >= 512 * 736) return;
  int oc = idx / 736, ci = idx - (idx / 736) * 736;
  float v[9];
#pragma unroll
  for (int k = 0; k < 9; ++k) v[k] = 0.f;
  if (ci < 720) {
    const float* src = w3 + ((size_t)oc * 720 + ci) * 9;
#pragma unroll
    for (int k = 0; k < 9; ++k) v[k] = src[k];
  }
#pragma unroll
  for (int k = 0; k < 9; ++k)
    Apack[((size_t)k * 512 + oc) * 736 + ci] = __float2bfloat16(v[k]);
}

// ---- K1: conv3x3 via MFMA implicit GEMM. Block: 128 oc x 128 px (one row) ----
__global__ __launch_bounds__(256) void conv_mfma_kernel(
    const float* __restrict__ feats, const __hip_bfloat16* __restrict__ Apack,
    __hip_bfloat16* __restrict__ X) {
  __shared__ short Blds[LDS_TOT];
  int gx = blockIdx.x;              // b*128 + h
  int oc_t = blockIdx.y;            // 0..3
  int b = gx >> 7, h = gx & 127;
  int tid = threadIdx.x;
  int wave = tid >> 6, lane = tid & 63;
  int wm = wave >> 1, wn = wave & 1;
  int l15 = lane & 15, quad = lane >> 4;

  f32x4 acc[4][4];
#pragma unroll
  for (int mb = 0; mb < 4; ++mb)
#pragma unroll
    for (int nb = 0; nb < 4; ++nb) acc[mb][nb] = (f32x4){0.f, 0.f, 0.f, 0.f};

  // zero halo columns w'=0 and w'=129 (never overwritten afterwards)
  for (int i = tid; i < 2 * LDS_ROW; i += 256) {
    int wp = (i < LDS_ROW) ? 0 : 129;
    Blds[wp * LDS_ROW + (i < LDS_ROW ? i : i - LDS_ROW)] = 0;
  }

  // staging roles: pair = 2 ci rows, sub = 8 columns
  int pair = tid >> 4;              // 0..15 -> ci' = 2*pair
  int sub = tid & 15;               // 0..15 -> cols sub*8 .. +7
  const short* Ab = (const short*)Apack;
  int oc_row = oc_t * 128 + wm * 64 + l15;

  for (int cb = 0; cb < 23; ++cb) {
    __syncthreads();  // previous iteration's reads done before overwrite
    // ---- stage 32 ci x 3 rows x 128 cols into LDS (transposed, bf16) ----
    int ci0 = cb * 32 + pair * 2;
#pragma unroll
    for (int r = 0; r < 3; ++r) {
      int hr = h - 1 + r;
      float lo[8], hi[8];
#pragma unroll
      for (int j = 0; j < 8; ++j) { lo[j] = 0.f; hi[j] = 0.f; }
      if ((unsigned)hr < 128u) {
        if (ci0 < 720) {
          const float4* s = (const float4*)(feats + (((size_t)b * 720 + ci0) << 14) + hr * 128 + sub * 8);
          float4 a0 = s[0], a1 = s[1];
          lo[0] = a0.x; lo[1] = a0.y; lo[2] = a0.z; lo[3] = a0.w;
          lo[4] = a1.x; lo[5] = a1.y; lo[6] = a1.z; lo[7] = a1.w;
        }
        if (ci0 + 1 < 720) {
          const float4* s = (const float4*)(feats + (((size_t)b * 720 + ci0 + 1) << 14) + hr * 128 + sub * 8);
          float4 a0 = s[0], a1 = s[1];
          hi[0] = a0.x; hi[1] = a0.y; hi[2] = a0.z; hi[3] = a0.w;
          hi[4] = a1.x; hi[5] = a1.y; hi[6] = a1.z; hi[7] = a1.w;
        }
      }
#pragma unroll
      for (int j = 0; j < 8; ++j) {
        int wp = sub * 8 + j + 1;  // w' = col + 1
        union { unsigned u; __hip_bfloat16 hh[2]; } P;
        P.hh[0] = __float2bfloat16(lo[j]);
        P.hh[1] = __float2bfloat16(hi[j]);
        *reinterpret_cast<unsigned*>(&Blds[wp * LDS_ROW + r * LDS_CI + pair * 2]) = P.u;
      }
    }
    __syncthreads();
    // ---- 9 shift-GEMM K-steps (K=32 each) ----
#pragma unroll
    for (int r = 0; r < 3; ++r) {
#pragma unroll
      for (int dw = 0; dw < 3; ++dw) {
        int plane = r * 3 + dw;
        const short* ap = Ab + ((size_t)plane * 512 + oc_row) * 736 + cb * 32 + quad * 8;
        bf16x8 af[4];
#pragma unroll
        for (int mb = 0; mb < 4; ++mb)
          af[mb] = *(const bf16x8*)(ap + (size_t)mb * 16 * 736);
        bf16x8 bfr[4];
#pragma unroll
        for (int nb = 0; nb < 4; ++nb) {
          int px = wn * 64 + nb * 16 + l15;
          bfr[nb] = *(const bf16x8*)(&Blds[(px + dw) * LDS_ROW + r * LDS_CI + quad * 8]);
        }
#pragma unroll
        for (int mb = 0; mb < 4; ++mb)
#pragma unroll
          for (int nb = 0; nb < 4; ++nb)
            acc[mb][nb] = __builtin_amdgcn_mfma_f32_16x16x32_bf16(
                af[mb], bfr[nb], acc[mb][nb], 0, 0, 0);
      }
    }
  }
  // ---- epilogue: D row = (quad*4+reg) within 16-oc block, col = l15 px ----
#pragma unroll
  for (int mb = 0; mb < 4; ++mb)
#pragma unroll
    for (int nb = 0; nb < 4; ++nb) {
      int px = wn * 64 + nb * 16 + l15;
#pragma unroll
      for (int reg = 0; reg < 4; ++reg) {
        int oc = oc_t * 128 + wm * 64 + mb * 16 + quad * 4 + reg;
        X[(((size_t)b * 512 + oc) << 14) + h * 128 + px] =
            __float2bfloat16(acc[mb][nb][reg]);
      }
    }
}

// ---- K2: per-channel BN stats -> scale/shift ----
__global__ __launch_bounds__(256) void bn_stats_kernel(
    const __hip_bfloat16* __restrict__ X, const float* __restrict__ gamma,
    const float* __restrict__ beta, float* __restrict__ ss_out) {
  int c = blockIdx.x, tid = threadIdx.x;
  float s = 0.f, ss = 0.f;
  for (int b = 0; b < 4; ++b) {
    const __hip_bfloat16* p = X + (((size_t)b * 512 + c) << 14);
    for (int n = tid * 8; n < 16384; n += 2048) {
      uint4 u = *reinterpret_cast<const uint4*>(p + n);
      unsigned arr[4] = {u.x, u.y, u.z, u.w};
#pragma unroll
      for (int j = 0; j < 4; ++j) {
        float f0 = u_lo(arr[j]), f1 = u_hi(arr[j]);
        s += f0 + f1;
        ss += f0 * f0 + f1 * f1;
      }
    }
  }
#pragma unroll
  for (int off = 32; off > 0; off >>= 1) {
    s += __shfl_down(s, off);
    ss += __shfl_down(ss, off);
  }
  __shared__ float red[8];
  int wid = tid >> 6, lane = tid & 63;
  if (lane == 0) { red[wid] = s; red[4 + wid] = ss; }
  __syncthreads();
  if (tid == 0) {
    s = red[0] + red[1] + red[2] + red[3];
    ss = red[4] + red[5] + red[6] + red[7];
    float mean = s * (1.f / 65536.f);
    float var = ss * (1.f / 65536.f) - mean * mean;
    float gi = gamma[c] * rsqrtf(var + 1e-5f);
    ss_out[c * 2] = gi;
    ss_out[c * 2 + 1] = beta[c] - mean * gi;
  }
}

// ---- K3: x = relu(y*scale+shift) in place (bf16) ----
__global__ __launch_bounds__(256) void bn_apply_kernel(
    __hip_bfloat16* __restrict__ X, const float* __restrict__ ss) {
  size_t idx = ((size_t)blockIdx.x * 256 + threadIdx.x) * 8;
  int c = (int)((idx >> 14) & 511);
  float sc = ss[c * 2], sh = ss[c * 2 + 1];
  uint4 u = *reinterpret_cast<const uint4*>(X + idx);
  unsigned arr[4] = {u.x, u.y, u.z, u.w};
  union { uint4 u; __hip_bfloat16 h[8]; } O;
#pragma unroll
  for (int j = 0; j < 4; ++j) {
    float f0 = fmaxf(fmaf(u_lo(arr[j]), sc, sh), 0.f);
    float f1 = fmaxf(fmaf(u_hi(arr[j]), sc, sh), 0.f);
    O.h[2 * j] = __float2bfloat16(f0);
    O.h[2 * j + 1] = __float2bfloat16(f1);
  }
  *reinterpret_cast<uint4*>(X + idx) = O.u;
}

// ---- K4: aux logits (regs) -> softmax -> ctx/psum accumulation ----
__global__ __launch_bounds__(256) void aux_ctx_kernel(
    const __hip_bfloat16* __restrict__ X, const float* __restrict__ aux_wt,
    const float* __restrict__ aux_b,
    float* __restrict__ ctx, float* __restrict__ psum) {
  int b = blockIdx.y;
  int n0 = blockIdx.x * 512;
  int tid = threadIdx.x;
  __shared__ float pl[19][512];

  const __hip_bfloat16* Xb = X + (((size_t)b * 512) << 14);

  int p0 = n0 + tid * 2;
  float a0[19], a1[19];
#pragma unroll
  for (int k = 0; k < 19; ++k) { a0[k] = aux_b[k]; a1[k] = a0[k]; }
  for (int c = 0; c < 512; ++c) {
    unsigned xv = *reinterpret_cast<const unsigned*>(Xb + ((size_t)c << 14) + p0);
    float f0 = u_lo(xv), f1 = u_hi(xv);
    const float* wr = aux_wt + c * 19;
#pragma unroll
    for (int k = 0; k < 19; ++k) {
      a0[k] = fmaf(wr[k], f0, a0[k]);
      a1[k] = fmaf(wr[k], f1, a1[k]);
    }
  }
  float mx0 = a0[0], mx1 = a1[0];
#pragma unroll
  for (int k = 1; k < 19; ++k) { mx0 = fmaxf(mx0, a0[k]); mx1 = fmaxf(mx1, a1[k]); }
  float s0 = 0.f, s1 = 0.f;
#pragma unroll
  for (int k = 0; k < 19; ++k) {
    a0[k] = __expf(a0[k] - mx0); s0 += a0[k];
    a1[k] = __expf(a1[k] - mx1); s1 += a1[k];
  }
  float r0 = 1.f / s0, r1 = 1.f / s1;
#pragma unroll
  for (int k = 0; k < 19; ++k) {
    float q0 = a0[k] * r0, q1 = a1[k] * r1;
    pl[k][tid * 2] = q0;
    pl[k][tid * 2 + 1] = q1;
    a0[k] = q0 + q1;
  }
#pragma unroll
  for (int k = 0; k < 19; ++k) {
    float t = a0[k];
#pragma unroll
    for (int off = 32; off > 0; off >>= 1) t += __shfl_down(t, off);
    if ((tid & 63) == 0) atomicAdd(&psum[b * 19 + k], t);
  }
  __syncthreads();

  int c0 = tid * 2;
  const __hip_bfloat16* x0 = Xb + ((size_t)c0 << 14) + n0;
  const __hip_bfloat16* x1 = x0 + 16384;
  float b0[19], b1[19];
#pragma unroll
  for (int k = 0; k < 19; ++k) { b0[k] = 0.f; b1[k] = 0.f; }
  for (int nl = 0; nl < 512; ++nl) {
    float xv0 = BF2F(x0[nl]), xv1 = BF2F(x1[nl]);
#pragma unroll
    for (int kk = 0; kk < 19; ++kk) {
      float p = pl[kk][nl];
      b0[kk] = fmaf(p, xv0, b0[kk]);
      b1[kk] = fmaf(p, xv1, b1[kk]);
    }
  }
#pragma unroll
  for (int kk = 0; kk < 19; ++kk) {
    atomicAdd(&ctx[((b * 19 + kk) << 9) + c0], b0[kk]);
    atomicAdd(&ctx[((b * 19 + kk) << 9) + c0 + 1], b1[kk]);
  }
}

// ---- K5: K = k_w@(ctx/psum)+k_b ; v = v_w@(ctx/psum)+v_b ; fcls = cls_w@out_w ----
__global__ __launch_bounds__(256) void small_a_kernel(
    const float* __restrict__ ctx, const float* __restrict__ psum,
    const float* __restrict__ k_w, const float* __restrict__ k_b,
    const float* __restrict__ v_w, const float* __restrict__ v_b,
    const float* __restrict__ cls_w, const float* __restrict__ out_w,
    float* __restrict__ Kmat, float* __restrict__ vmat, float* __restrict__ fcls) {
  int i = blockIdx.x * 256 + threadIdx.x;
  if (i < 38912) {
    int half = i / 19456;
    int j = i - half * 19456;
    int d = j & 255;
    int t = j >> 8;
    const float* w = (half ? v_w : k_w) + d * 512;
    const float* cr = ctx + (t << 9);
    float s = 0.f;
    for (int c = 0; c < 512; ++c) s = fmaf(w[c], cr[c], s);
    float rcp = 1.f / fmaxf(psum[t], 1e-6f);
    float bias = (half ? v_b : k_b)[d];
    (half ? vmat : Kmat)[j] = s * rcp + bias;
  } else if (i < 43776) {
    int j = i - 38912;
    int vv = j & 255, k = j >> 8;
    const float* cw = cls_w + k * 512;
    float s = 0.f;
    for (int c = 0; c < 512; ++c) s = fmaf(cw[c], out_w[c * 256 + vv], s);
    fcls[j] = s;
  }
}

// ---- K6: m_t and g ----
__global__ __launch_bounds__(256) void small_b_kernel(
    const float* __restrict__ Kmat, const float* __restrict__ vmat,
    const float* __restrict__ fcls, const float* __restrict__ q_w,
    float* __restrict__ m_t, float* __restrict__ g) {
  int i = blockIdx.x * 256 + threadIdx.x;
  if (i < 38912) {
    int kk = i % 19;
    int t = i / 19;
    int c = t & 511, b = t >> 9;
    const float* kr = Kmat + ((b * 19 + kk) << 8);
    float s = 0.f;
    for (int d = 0; d < 256; ++d) s = fmaf(q_w[d * 512 + c], kr[d], s);
    m_t[i] = s;
  } else if (i < 40356) {
    int j = i - 38912;
    int k = j % 19;
    int t = j / 19;
    const float* vr = vmat + (t << 8);
    const float* fr = fcls + (k << 8);
    float s = 0.f;
    for (int v = 0; v < 256; ++v) s = fmaf(fr[v], vr[v], s);
    g[j] = s;
  }
}

// ---- K7: fused attn-softmax + final logits (writes logits half only) ----
__global__ __launch_bounds__(256) void final_fused_kernel(
    const __hip_bfloat16* __restrict__ X, const float* __restrict__ m_t,
    const float* __restrict__ cls_wt, const float* __restrict__ cls_b,
    const float* __restrict__ g, float* __restrict__ out) {
  int b = blockIdx.y;
  int n = blockIdx.x * 256 + threadIdx.x;
  float macc[19], cacc[19];
#pragma unroll
  for (int k = 0; k < 19; ++k) { macc[k] = 0.f; cacc[k] = 0.f; }
  const __hip_bfloat16* xp = X + (((size_t)b * 512) << 14) + n;
  for (int c = 0; c < 512; ++c) {
    float xv = BF2F(xp[(size_t)c << 14]);
    const float* mr = m_t + (b * 512 + c) * 19;
    const float* wr = cls_wt + c * 19;
#pragma unroll
    for (int k = 0; k < 19; ++k) {
      macc[k] = fmaf(mr[k], xv, macc[k]);
      cacc[k] = fmaf(wr[k], xv, cacc[k]);
    }
  }
  float mx = -1e30f;
#pragma unroll
  for (int k = 0; k < 19; ++k) { macc[k] *= 0.0625f; mx = fmaxf(mx, macc[k]); }
  float sum = 0.f;
#pragma unroll
  for (int k = 0; k < 19; ++k) { macc[k] = __expf(macc[k] - mx); sum += macc[k]; }
  float r = 1.f / sum;
#pragma unroll
  for (int k = 0; k < 19; ++k) cacc[k] += cls_b[k];
#pragma unroll
  for (int kk = 0; kk < 19; ++kk) {
    float av = macc[kk] * r;
    const float* gr = g + (b * 19 + kk) * 19;
#pragma unroll
    for (int k = 0; k < 19; ++k) cacc[k] = fmaf(gr[k], av, cacc[k]);
  }
  size_t ob = ((size_t)b * 19) << 14;
#pragma unroll
  for (int k = 0; k < 19; ++k)
    out[ob + ((size_t)k << 14) + n] = scrub(cacc[k]);
}

// ---- K8 (LAST): recompute aux logits f32, overwriting aux-half scratch ----
__global__ __launch_bounds__(256) void aux_final_kernel(
    const __hip_bfloat16* __restrict__ X, const float* __restrict__ aux_w,
    const float* __restrict__ aux_b, float* __restrict__ aux_out) {
  __shared__ float wt[9728];
  for (int i = threadIdx.x; i < 9728; i += 256) {
    int k = i >> 9, c = i & 511;
    wt[c * 19 + k] = aux_w[i];
  }
  __syncthreads();
  int b = blockIdx.y;
  int n = blockIdx.x * 256 + threadIdx.x;
  float acc[19];
#pragma unroll
  for (int k = 0; k < 19; ++k) acc[k] = aux_b[k];
  const __hip_bfloat16* xp = X + (((size_t)b * 512) << 14) + n;
  for (int c = 0; c < 512; ++c) {
    float xv = BF2F(xp[(size_t)c << 14]);
    const float* wr = &wt[c * 19];
#pragma unroll
    for (int k = 0; k < 19; ++k) acc[k] = fmaf(wr[k], xv, acc[k]);
  }
  size_t ob = ((size_t)b * 19) << 14;
#pragma unroll
  for (int k = 0; k < 19; ++k)
    aux_out[ob + ((size_t)k << 14) + n] = scrub(acc[k]);
}

extern "C" void kernel_launch(void* const* d_in, const int* in_sizes, int n_in,
                              void* d_out, int out_size, void* d_ws, size_t ws_size,
                              hipStream_t stream) {
  const float* feats = (const float*)d_in[0];
  const float* w3    = (const float*)d_in[1];
  const float* gamma = (const float*)d_in[2];
  const float* beta  = (const float*)d_in[3];
  const float* aux_w = (const float*)d_in[4];
  const float* aux_b = (const float*)d_in[5];
  const float* q_w   = (const float*)d_in[6];
  const float* k_w   = (const float*)d_in[7];
  const float* k_b   = (const float*)d_in[8];
  const float* v_w   = (const float*)d_in[9];
  const float* v_b   = (const float*)d_in[10];
  const float* out_w = (const float*)d_in[11];
  const float* cls_w = (const float*)d_in[12];
  const float* cls_b = (const float*)d_in[13];

  float* logits_out = (float*)d_out;
  float* aux_out    = logits_out + 1245184;

  __hip_bfloat16* X = (__hip_bfloat16*)d_ws;  // 64 MiB

  char* ob = (char*)d_out;
  __hip_bfloat16* Apack = (__hip_bfloat16*)(ob + SO_APACK);
  float* aux_wt = (float*)(ob + TA_AUXWT);
  float* cls_wt = (float*)(ob + TA_CLSWT);
  float* ssbuf  = (float*)(ob + TA_SS);
  float* psum   = (float*)(ob + TA_PSUM);
  float* ctx    = (float*)(ob + TA_CTX);
  float* Kmat   = (float*)(ob + TA_KMAT);
  float* vmat   = (float*)(ob + TA_VMAT);
  float* fcls   = (float*)(ob + TA_FCLS);
  float* m_t    = (float*)(ob + TA_MT);
  float* g      = (float*)(ob + TA_G);

  hipMemsetAsync(ob + TA_PSUM, 0, 512 + 155648, stream);

  prep_small_kernel<<<38, 256, 0, stream>>>(aux_w, cls_w, aux_wt, cls_wt);
  prep_apack_kernel<<<1472, 256, 0, stream>>>(w3, Apack);
  conv_mfma_kernel<<<dim3(512, 4), 256, 0, stream>>>(feats, Apack, X);
  bn_stats_kernel<<<512, 256, 0, stream>>>(X, gamma, beta, ssbuf);
  bn_apply_kernel<<<16384, 256, 0, stream>>>(X, ssbuf);
  aux_ctx_kernel<<<dim3(32, 4), 256, 0, stream>>>(X, aux_wt, aux_b, ctx, psum);
  small_a_kernel<<<171, 256, 0, stream>>>(ctx, psum, k_w, k_b, v_w, v_b, cls_w, out_w,
                                          Kmat, vmat, fcls);
  small_b_kernel<<<158, 256, 0, stream>>>(Kmat, vmat, fcls, q_w, m_t, g);
  final_fused_kernel<<<dim3(64, 4), 256, 0, stream>>>(X, m_t, cls_wt, cls_b, g, logits_out);
  aux_final_kernel<<<dim3(64, 4), 256, 0, stream>>>(X, aux_w, aux_b, aux_out);
}